// Round 3
// baseline (485.469 us; speedup 1.0000x reference)
//
#include <hip/hip_runtime.h>

#define TPB 256

// workspace float offsets (prep-kernel output layout)
#define OFF_CE   0        // [4][128]  W1[o,0]+W1[o,6+e]+b1[o]
#define OFF_A    512      // [3][128]  W1[o,10+k]
#define OFF_W2T  896      // [128][40] W2[j,o] transposed, j-padded to 40
#define OFF_B2   6016     // [48]
#define OFF_W3   6064     // [128][40] W3[o,j], j-padded
#define OFF_B3   11184    // [128]
#define OFF_MV   11312    // [128][16] k<8: Wm[k,o], k>=8: Wv[k-8,o]
#define OFF_BMV  13360    // [16]
#define OFF_D1C  13376    // [32]  Wd1[o,0]+bd1[o]
#define OFF_D1T  13408    // [20][32] Wd1[o,5+j] transposed (j=12..19 -> z cols 17..24)
#define OFF_D2   14048    // [12][32]
#define OFF_BD2  14432    // [16]

__global__ void prep_kernel(
    const float* __restrict__ W1, const float* __restrict__ b1,
    const float* __restrict__ W2, const float* __restrict__ b2,
    const float* __restrict__ W3, const float* __restrict__ b3,
    const float* __restrict__ Wm, const float* __restrict__ bm,
    const float* __restrict__ Wv, const float* __restrict__ bv,
    const float* __restrict__ Wd1, const float* __restrict__ bd1,
    const float* __restrict__ Wd2, const float* __restrict__ bd2,
    float* __restrict__ w)
{
    const int t = threadIdx.x;
    for (int i = t; i < 512; i += TPB) {       // cE = W1[:,0] + W1[:,6+e] + b1
        int e = i >> 7, o = i & 127;
        w[OFF_CE + i] = W1[o * 13 + 0] + W1[o * 13 + 6 + e] + b1[o];
    }
    for (int i = t; i < 384; i += TPB) {       // A = W1[:,10+k]
        int k = i >> 7, o = i & 127;
        w[OFF_A + i] = W1[o * 13 + 10 + k];
    }
    for (int i = t; i < 128 * 40; i += TPB) {  // W2 transposed, padded
        int o = i / 40, j = i % 40;
        w[OFF_W2T + i] = (j < 39) ? W2[j * 128 + o] : 0.f;
    }
    for (int i = t; i < 48; i += TPB) w[OFF_B2 + i] = (i < 39) ? b2[i] : 0.f;
    for (int i = t; i < 128 * 40; i += TPB) {  // W3 padded
        int o = i / 40, j = i % 40;
        w[OFF_W3 + i] = (j < 39) ? W3[o * 39 + j] : 0.f;
    }
    for (int i = t; i < 128; i += TPB) w[OFF_B3 + i] = b3[i];
    for (int i = t; i < 2048; i += TPB) {      // Wm/Wv interleaved [o][16]
        int o = i >> 4, k = i & 15;
        w[OFF_MV + i] = (k < 8) ? Wm[k * 128 + o] : Wv[(k - 8) * 128 + o];
    }
    for (int i = t; i < 16; i += TPB) w[OFF_BMV + i] = (i < 8) ? bm[i] : bv[i - 8];
    for (int i = t; i < 32; i += TPB) w[OFF_D1C + i] = Wd1[i * 25 + 0] + bd1[i];
    for (int i = t; i < 640; i += TPB) {       // Wd1 cols 5..24 transposed
        int j = i >> 5, o = i & 31;
        w[OFF_D1T + i] = Wd1[o * 25 + 5 + j];
    }
    for (int i = t; i < 384; i += TPB) w[OFF_D2 + i] = Wd2[i];
    for (int i = t; i < 16; i += TPB) w[OFF_BD2 + i] = (i < 12) ? bd2[i] : 0.f;
}

// columns {0,1,2,3, 10,11,12,13, 14,18,22,26} of a 30-float row
__device__ __forceinline__ void extract12(const float* r, float* v) {
    v[0] = r[0];  v[1] = r[1];  v[2] = r[2];  v[3] = r[3];
    v[4] = r[10]; v[5] = r[11]; v[6] = r[12]; v[7] = r[13];
    v[8] = r[14]; v[9] = r[18]; v[10] = r[22]; v[11] = r[26];
}

__global__ __launch_bounds__(TPB) void vae_fused(
    const float* __restrict__ ic, const float* __restrict__ cc,
    const float4* __restrict__ epsq,
    const float* __restrict__ w,
    float* __restrict__ out, int B)
{
    __shared__ float sbuf[TPB * 30];
    const int tid = threadIdx.x;
    const int n = 30 * TPB;
    const int base = blockIdx.x * n;
    const int b = blockIdx.x * TPB + tid;

    // eps: 8 floats per row
    float4 e0 = epsq[2 * b];
    float4 e1 = epsq[2 * b + 1];
    float epsv[8] = { e0.x, e0.y, e0.z, e0.w, e1.x, e1.y, e1.z, e1.w };

    // stage current_c (coalesced), extract, then reuse buffer for initial_c
    for (int i = tid; i < n; i += TPB) sbuf[i] = cc[base + i];
    __syncthreads();
    float cv[12];
    extract12(&sbuf[tid * 30], cv);
    __syncthreads();
    for (int i = tid; i < n; i += TPB) sbuf[i] = ic[base + i];
    __syncthreads();
    float icv[12];
    extract12(&sbuf[tid * 30], icv);

    // ---- message MLP over 4 edges, summed after relu
    float ssum[39];
    #pragma unroll
    for (int j = 0; j < 39; j++) ssum[j] = 0.f;

    #pragma unroll
    for (int e = 0; e < 4; e++) {
        const float p0 = cv[e], p1 = cv[4 + e], p2 = cv[8 + e];
        float acc[39];
        #pragma unroll
        for (int j = 0; j < 39; j++) acc[j] = w[OFF_B2 + j];
        #pragma unroll 2
        for (int o = 0; o < 128; o++) {
            float t = w[OFF_CE + e * 128 + o];
            t = fmaf(w[OFF_A + o], p0, t);
            t = fmaf(w[OFF_A + 128 + o], p1, t);
            t = fmaf(w[OFF_A + 256 + o], p2, t);
            t = fmaxf(t, 0.f);
            #pragma unroll
            for (int j = 0; j < 39; j++)
                acc[j] = fmaf(w[OFF_W2T + o * 40 + j], t, acc[j]);
        }
        #pragma unroll
        for (int j = 0; j < 39; j++) ssum[j] += fmaxf(acc[j], 0.f);
    }

    // ---- x3 = relu(W3 @ ssum + b3); means/logvar accumulated on the fly
    float m[16];
    #pragma unroll
    for (int k = 0; k < 16; k++) m[k] = w[OFF_BMV + k];
    #pragma unroll 2
    for (int o = 0; o < 128; o++) {
        float t = w[OFF_B3 + o];
        #pragma unroll
        for (int j = 0; j < 39; j++)
            t = fmaf(w[OFF_W3 + o * 40 + j], ssum[j], t);
        t = fmaxf(t, 0.f);
        #pragma unroll
        for (int k = 0; k < 16; k++)
            m[k] = fmaf(w[OFF_MV + o * 16 + k], t, m[k]);
    }

    // ---- reparameterization
    float zf[8];
    #pragma unroll
    for (int k = 0; k < 8; k++)
        zf[k] = fmaf(epsv[k], __expf(0.5f * m[8 + k]), m[k]);

    // ---- decoder
    float h[32];
    #pragma unroll
    for (int o = 0; o < 32; o++) h[o] = w[OFF_D1C + o];
    #pragma unroll
    for (int j = 0; j < 12; j++) {
        #pragma unroll
        for (int o = 0; o < 32; o++)
            h[o] = fmaf(w[OFF_D1T + j * 32 + o], icv[j], h[o]);
    }
    #pragma unroll
    for (int k = 0; k < 8; k++) {
        #pragma unroll
        for (int o = 0; o < 32; o++)
            h[o] = fmaf(w[OFF_D1T + (12 + k) * 32 + o], zf[k], h[o]);
    }
    #pragma unroll
    for (int o = 0; o < 32; o++) h[o] = fmaxf(h[o], 0.f);

    float rec[12];
    #pragma unroll
    for (int rr = 0; rr < 12; rr++) {
        float a = w[OFF_BD2 + rr];
        #pragma unroll
        for (int o = 0; o < 32; o++)
            a = fmaf(w[OFF_D2 + rr * 32 + o], h[o], a);
        rec[rr] = 1.f / (1.f + __expf(-a));
    }

    // ---- fp32 stores: recon [B,12] | means [B,8] | logvar [B,8] | z [B,8]
    float4* out4 = (float4*)out;
    out4[b * 3 + 0] = make_float4(rec[0], rec[1], rec[2], rec[3]);
    out4[b * 3 + 1] = make_float4(rec[4], rec[5], rec[6], rec[7]);
    out4[b * 3 + 2] = make_float4(rec[8], rec[9], rec[10], rec[11]);

    const int mbase = B * 3 + 2 * b;   // float4 index of means row
    const int lbase = B * 5 + 2 * b;
    const int zbase = B * 7 + 2 * b;
    out4[mbase + 0] = make_float4(m[0], m[1], m[2], m[3]);
    out4[mbase + 1] = make_float4(m[4], m[5], m[6], m[7]);
    out4[lbase + 0] = make_float4(m[8], m[9], m[10], m[11]);
    out4[lbase + 1] = make_float4(m[12], m[13], m[14], m[15]);
    out4[zbase + 0] = make_float4(zf[0], zf[1], zf[2], zf[3]);
    out4[zbase + 1] = make_float4(zf[4], zf[5], zf[6], zf[7]);
}

extern "C" void kernel_launch(void* const* d_in, const int* in_sizes, int n_in,
                              void* d_out, int out_size, void* d_ws, size_t ws_size,
                              hipStream_t stream) {
    const float* ic  = (const float*)d_in[0];   // initial_c [B,30]
    // d_in[1] initial_s — unused by the reference
    const float* cc  = (const float*)d_in[2];   // current_c [B,30]
    const float* eps = (const float*)d_in[3];   // eps [B,8]

    float* w = (float*)d_ws;
    const int B = in_sizes[3] / 8;              // 262144
    const int nblocks = B / TPB;                // 1024

    prep_kernel<<<1, TPB, 0, stream>>>(
        (const float*)d_in[4],  (const float*)d_in[5],
        (const float*)d_in[6],  (const float*)d_in[7],
        (const float*)d_in[8],  (const float*)d_in[9],
        (const float*)d_in[10], (const float*)d_in[11],
        (const float*)d_in[12], (const float*)d_in[13],
        (const float*)d_in[14], (const float*)d_in[15],
        (const float*)d_in[16], (const float*)d_in[17], w);
    vae_fused<<<nblocks, TPB, 0, stream>>>(ic, cc, (const float4*)eps, w,
                                           (float*)d_out, B);
}

// Round 4
// 458.786 us; speedup vs baseline: 1.0582x; 1.0582x over previous
//
#include <hip/hip_runtime.h>

#define TPB 256
#define PREP_BLOCKS 16

// workspace float offsets (prep-kernel output layout)
#define OFF_CE   0        // [4][128]  W1[o,0]+W1[o,6+e]+b1[o]
#define OFF_A    512      // [3][128]  W1[o,10+k]
#define OFF_W2T  896      // [128][40] W2[j,o] transposed, j-padded to 40
#define OFF_B2   6016     // [48]
#define OFF_W3   6064     // [128][40] W3[o,j], j-padded
#define OFF_B3   11184    // [128]
#define OFF_MV   11312    // [128][16] k<8: Wm[k,o], k>=8: Wv[k-8,o]
#define OFF_BMV  13360    // [16]
#define OFF_D1C  13376    // [32]  Wd1[o,0]+bd1[o]
#define OFF_D1T  13408    // [20][32] Wd1[o,5+j] transposed (j=12..19 -> z cols)
#define OFF_D2   14048    // [12][32]
#define OFF_BD2  14432    // [16]

__global__ void prep_kernel(
    const float* __restrict__ W1, const float* __restrict__ b1,
    const float* __restrict__ W2, const float* __restrict__ b2,
    const float* __restrict__ W3, const float* __restrict__ b3,
    const float* __restrict__ Wm, const float* __restrict__ bm,
    const float* __restrict__ Wv, const float* __restrict__ bv,
    const float* __restrict__ Wd1, const float* __restrict__ bd1,
    const float* __restrict__ Wd2, const float* __restrict__ bd2,
    float* __restrict__ w)
{
    const int g = blockIdx.x * TPB + threadIdx.x;
    const int gs = gridDim.x * TPB;
    for (int i = g; i < 512; i += gs) {       // cE = W1[:,0] + W1[:,6+e] + b1
        int e = i >> 7, o = i & 127;
        w[OFF_CE + i] = W1[o * 13 + 0] + W1[o * 13 + 6 + e] + b1[o];
    }
    for (int i = g; i < 384; i += gs) {       // A = W1[:,10+k]
        int k = i >> 7, o = i & 127;
        w[OFF_A + i] = W1[o * 13 + 10 + k];
    }
    for (int i = g; i < 128 * 40; i += gs) {  // W2 transposed, padded
        int o = i / 40, j = i % 40;
        w[OFF_W2T + i] = (j < 39) ? W2[j * 128 + o] : 0.f;
    }
    for (int i = g; i < 48; i += gs) w[OFF_B2 + i] = (i < 39) ? b2[i] : 0.f;
    for (int i = g; i < 128 * 40; i += gs) {  // W3 padded
        int o = i / 40, j = i % 40;
        w[OFF_W3 + i] = (j < 39) ? W3[o * 39 + j] : 0.f;
    }
    for (int i = g; i < 128; i += gs) w[OFF_B3 + i] = b3[i];
    for (int i = g; i < 2048; i += gs) {      // Wm/Wv interleaved [o][16]
        int o = i >> 4, k = i & 15;
        w[OFF_MV + i] = (k < 8) ? Wm[k * 128 + o] : Wv[(k - 8) * 128 + o];
    }
    for (int i = g; i < 16; i += gs) w[OFF_BMV + i] = (i < 8) ? bm[i] : bv[i - 8];
    for (int i = g; i < 32; i += gs) w[OFF_D1C + i] = Wd1[i * 25 + 0] + bd1[i];
    for (int i = g; i < 640; i += gs) {       // Wd1 cols 5..24 transposed
        int j = i >> 5, o = i & 31;
        w[OFF_D1T + i] = Wd1[o * 25 + 5 + j];
    }
    for (int i = g; i < 384; i += gs) w[OFF_D2 + i] = Wd2[i];
    for (int i = g; i < 16; i += gs) w[OFF_BD2 + i] = (i < 12) ? bd2[i] : 0.f;
}

// load columns {0,1,2,3, 10,11,12,13, 14,18,22,26} of a 30-float row directly
// from global. row base = p + 120*b bytes (8-byte aligned) -> float2-safe.
__device__ __forceinline__ void load12(const float* __restrict__ p, long b, float* v) {
    const float* r = p + b * 30;
    const float2* r2 = (const float2*)r;
    float2 a0 = r2[0], a1 = r2[1];   // cols 0..3
    float2 a5 = r2[5], a6 = r2[6];   // cols 10..13
    v[0] = a0.x; v[1] = a0.y; v[2] = a1.x; v[3] = a1.y;
    v[4] = a5.x; v[5] = a5.y; v[6] = a6.x; v[7] = a6.y;
    v[8] = r[14]; v[9] = r[18]; v[10] = r[22]; v[11] = r[26];
}

__global__ __launch_bounds__(TPB) void vae_fused(
    const float* __restrict__ ic, const float* __restrict__ cc,
    const float4* __restrict__ epsq,
    const float* __restrict__ w,
    float* __restrict__ out, int B)
{
    const int tid = threadIdx.x;
    const long b = blockIdx.x * TPB + tid;

    // eps: 8 floats per row (16B-aligned)
    float4 e0 = epsq[2 * b];
    float4 e1 = epsq[2 * b + 1];
    float epsv[8] = { e0.x, e0.y, e0.z, e0.w, e1.x, e1.y, e1.z, e1.w };

    float cv[12], icv[12];
    load12(cc, b, cv);
    load12(ic, b, icv);

    // ---- message MLP over 4 edges, summed after relu
    float ssum[39];
    #pragma unroll
    for (int j = 0; j < 39; j++) ssum[j] = 0.f;

    #pragma unroll
    for (int e = 0; e < 4; e++) {
        const float p0 = cv[e], p1 = cv[4 + e], p2 = cv[8 + e];
        float acc[39];
        #pragma unroll
        for (int j = 0; j < 39; j++) acc[j] = w[OFF_B2 + j];
        #pragma unroll 2
        for (int o = 0; o < 128; o++) {
            float t = w[OFF_CE + e * 128 + o];
            t = fmaf(w[OFF_A + o], p0, t);
            t = fmaf(w[OFF_A + 128 + o], p1, t);
            t = fmaf(w[OFF_A + 256 + o], p2, t);
            t = fmaxf(t, 0.f);
            #pragma unroll
            for (int j = 0; j < 39; j++)
                acc[j] = fmaf(w[OFF_W2T + o * 40 + j], t, acc[j]);
        }
        #pragma unroll
        for (int j = 0; j < 39; j++) ssum[j] += fmaxf(acc[j], 0.f);
    }

    // ---- x3 = relu(W3 @ ssum + b3); means/logvar accumulated on the fly
    float m[16];
    #pragma unroll
    for (int k = 0; k < 16; k++) m[k] = w[OFF_BMV + k];
    #pragma unroll 2
    for (int o = 0; o < 128; o++) {
        float t = w[OFF_B3 + o];
        #pragma unroll
        for (int j = 0; j < 39; j++)
            t = fmaf(w[OFF_W3 + o * 40 + j], ssum[j], t);
        t = fmaxf(t, 0.f);
        #pragma unroll
        for (int k = 0; k < 16; k++)
            m[k] = fmaf(w[OFF_MV + o * 16 + k], t, m[k]);
    }

    // ---- reparameterization
    float zf[8];
    #pragma unroll
    for (int k = 0; k < 8; k++)
        zf[k] = fmaf(epsv[k], __expf(0.5f * m[8 + k]), m[k]);

    // ---- decoder
    float h[32];
    #pragma unroll
    for (int o = 0; o < 32; o++) h[o] = w[OFF_D1C + o];
    #pragma unroll
    for (int j = 0; j < 12; j++) {
        #pragma unroll
        for (int o = 0; o < 32; o++)
            h[o] = fmaf(w[OFF_D1T + j * 32 + o], icv[j], h[o]);
    }
    #pragma unroll
    for (int k = 0; k < 8; k++) {
        #pragma unroll
        for (int o = 0; o < 32; o++)
            h[o] = fmaf(w[OFF_D1T + (12 + k) * 32 + o], zf[k], h[o]);
    }
    #pragma unroll
    for (int o = 0; o < 32; o++) h[o] = fmaxf(h[o], 0.f);

    float rec[12];
    #pragma unroll
    for (int rr = 0; rr < 12; rr++) {
        float a = w[OFF_BD2 + rr];
        #pragma unroll
        for (int o = 0; o < 32; o++)
            a = fmaf(w[OFF_D2 + rr * 32 + o], h[o], a);
        rec[rr] = 1.f / (1.f + __expf(-a));
    }

    // ---- fp32 stores: recon [B,12] | means [B,8] | logvar [B,8] | z [B,8]
    float4* out4 = (float4*)out;
    out4[b * 3 + 0] = make_float4(rec[0], rec[1], rec[2], rec[3]);
    out4[b * 3 + 1] = make_float4(rec[4], rec[5], rec[6], rec[7]);
    out4[b * 3 + 2] = make_float4(rec[8], rec[9], rec[10], rec[11]);

    const long mbase = (long)B * 3 + 2 * b;   // float4 index of means row
    const long lbase = (long)B * 5 + 2 * b;
    const long zbase = (long)B * 7 + 2 * b;
    out4[mbase + 0] = make_float4(m[0], m[1], m[2], m[3]);
    out4[mbase + 1] = make_float4(m[4], m[5], m[6], m[7]);
    out4[lbase + 0] = make_float4(m[8], m[9], m[10], m[11]);
    out4[lbase + 1] = make_float4(m[12], m[13], m[14], m[15]);
    out4[zbase + 0] = make_float4(zf[0], zf[1], zf[2], zf[3]);
    out4[zbase + 1] = make_float4(zf[4], zf[5], zf[6], zf[7]);
}

extern "C" void kernel_launch(void* const* d_in, const int* in_sizes, int n_in,
                              void* d_out, int out_size, void* d_ws, size_t ws_size,
                              hipStream_t stream) {
    const float* ic  = (const float*)d_in[0];   // initial_c [B,30]
    // d_in[1] initial_s — unused by the reference
    const float* cc  = (const float*)d_in[2];   // current_c [B,30]
    const float* eps = (const float*)d_in[3];   // eps [B,8]

    float* w = (float*)d_ws;
    const int B = in_sizes[3] / 8;              // 262144
    const int nblocks = B / TPB;                // 1024

    prep_kernel<<<PREP_BLOCKS, TPB, 0, stream>>>(
        (const float*)d_in[4],  (const float*)d_in[5],
        (const float*)d_in[6],  (const float*)d_in[7],
        (const float*)d_in[8],  (const float*)d_in[9],
        (const float*)d_in[10], (const float*)d_in[11],
        (const float*)d_in[12], (const float*)d_in[13],
        (const float*)d_in[14], (const float*)d_in[15],
        (const float*)d_in[16], (const float*)d_in[17], w);
    vae_fused<<<nblocks, TPB, 0, stream>>>(ic, cc, (const float4*)eps, w,
                                           (float*)d_out, B);
}

// Round 5
// 404.550 us; speedup vs baseline: 1.2000x; 1.1341x over previous
//
#include <hip/hip_runtime.h>

#define TPB 512

// LDS float offsets (all 16B-aligned)
#define L_CEA   0        // [4][128][4] {ce(e,o), a0(o), a1(o), a2(o)}
#define L_W2T   2048     // [128][40]  W2[j,o] transposed, j-padded to 40
#define L_B2    7168     // [40]
#define L_W3    7208     // [128][40]  W3[o,j], j-padded to 40
#define L_B3    12328    // [128]
#define L_MV    12456    // [128][16]  k<8: Wm[k,o], k>=8: Wv[k-8,o]
#define L_BMV   14504    // [16]
#define L_D1C   14520    // [32]  Wd1[o,0]+bd1[o]
#define L_D1T   14552    // [20][32] Wd1[o,5+j] transposed
#define L_D2    15192    // [12][32]
#define L_BD2   15576    // [16]
#define L_TOT   15592    // floats (~60.9 KB)

// load columns {0,1,2,3, 10,11,12,13, 14,18,22,26} of a 30-float row
__device__ __forceinline__ void load12(const float* __restrict__ p, long b, float* v) {
    const float* r = p + b * 30;
    const float2* r2 = (const float2*)r;
    float2 a0 = r2[0], a1 = r2[1];   // cols 0..3
    float2 a5 = r2[5], a6 = r2[6];   // cols 10..13
    v[0] = a0.x; v[1] = a0.y; v[2] = a1.x; v[3] = a1.y;
    v[4] = a5.x; v[5] = a5.y; v[6] = a6.x; v[7] = a6.y;
    v[8] = r[14]; v[9] = r[18]; v[10] = r[22]; v[11] = r[26];
}

__global__ __launch_bounds__(TPB, 4) void vae_fused(
    const float* __restrict__ ic, const float* __restrict__ cc,
    const float* __restrict__ eps,
    const float* __restrict__ W1, const float* __restrict__ b1,
    const float* __restrict__ W2, const float* __restrict__ b2,
    const float* __restrict__ W3, const float* __restrict__ b3,
    const float* __restrict__ Wm, const float* __restrict__ bm,
    const float* __restrict__ Wv, const float* __restrict__ bv,
    const float* __restrict__ Wd1, const float* __restrict__ bd1,
    const float* __restrict__ Wd2, const float* __restrict__ bd2,
    float* __restrict__ out, int B)
{
    __shared__ __align__(16) float sw[L_TOT];
    const int tid = threadIdx.x;

    // ---- per-block weight prep: global -> LDS (redundant across blocks, cheap)
    for (int i = tid; i < 2048; i += TPB) {       // CEA pack
        int e = i >> 9, r = i & 511, o = r >> 2, c = i & 3;
        float v;
        if (c == 0)      v = W1[o * 13 + 0] + W1[o * 13 + 6 + e] + b1[o];
        else             v = W1[o * 13 + 9 + c];   // a_{c-1} = W1[o,10+(c-1)]
        sw[L_CEA + i] = v;
    }
    for (int i = tid; i < 5120; i += TPB) {       // W2 transposed, padded
        int o = i / 40, j = i % 40;
        sw[L_W2T + i] = (j < 39) ? W2[j * 128 + o] : 0.f;
    }
    for (int i = tid; i < 40; i += TPB) sw[L_B2 + i] = (i < 39) ? b2[i] : 0.f;
    for (int i = tid; i < 5120; i += TPB) {       // W3 padded
        int o = i / 40, j = i % 40;
        sw[L_W3 + i] = (j < 39) ? W3[o * 39 + j] : 0.f;
    }
    for (int i = tid; i < 128; i += TPB) sw[L_B3 + i] = b3[i];
    for (int i = tid; i < 2048; i += TPB) {       // Wm/Wv interleaved [o][16]
        int o = i >> 4, k = i & 15;
        sw[L_MV + i] = (k < 8) ? Wm[k * 128 + o] : Wv[(k - 8) * 128 + o];
    }
    for (int i = tid; i < 16; i += TPB) sw[L_BMV + i] = (i < 8) ? bm[i] : bv[i - 8];
    for (int i = tid; i < 32; i += TPB) sw[L_D1C + i] = Wd1[i * 25 + 0] + bd1[i];
    for (int i = tid; i < 640; i += TPB) {        // Wd1 cols 5..24 transposed
        int j = i >> 5, o = i & 31;
        sw[L_D1T + i] = Wd1[o * 25 + 5 + j];
    }
    for (int i = tid; i < 384; i += TPB) sw[L_D2 + i] = Wd2[i];
    for (int i = tid; i < 16; i += TPB) sw[L_BD2 + i] = (i < 12) ? bd2[i] : 0.f;
    __syncthreads();

    const long b = (long)blockIdx.x * TPB + tid;

    float cv[12];
    load12(cc, b, cv);

    // ---- message MLP over 4 edges, summed after relu (40-padded)
    float ssum[40];
    #pragma unroll
    for (int j = 0; j < 40; j++) ssum[j] = 0.f;

    const float4* cea4 = (const float4*)&sw[L_CEA];
    const float4* b24  = (const float4*)&sw[L_B2];

    #pragma unroll
    for (int e = 0; e < 4; e++) {
        const float p0 = cv[e], p1 = cv[4 + e], p2 = cv[8 + e];
        float acc[40];
        #pragma unroll
        for (int j = 0; j < 10; j++) {
            float4 bj = b24[j];
            acc[4 * j] = bj.x; acc[4 * j + 1] = bj.y;
            acc[4 * j + 2] = bj.z; acc[4 * j + 3] = bj.w;
        }
        #pragma unroll 2
        for (int o = 0; o < 128; o++) {
            float4 ca = cea4[e * 128 + o];
            float t = ca.x;
            t = fmaf(ca.y, p0, t);
            t = fmaf(ca.z, p1, t);
            t = fmaf(ca.w, p2, t);
            t = fmaxf(t, 0.f);
            const float4* w2r = (const float4*)&sw[L_W2T + o * 40];
            #pragma unroll
            for (int j = 0; j < 10; j++) {
                float4 wv = w2r[j];
                acc[4 * j]     = fmaf(wv.x, t, acc[4 * j]);
                acc[4 * j + 1] = fmaf(wv.y, t, acc[4 * j + 1]);
                acc[4 * j + 2] = fmaf(wv.z, t, acc[4 * j + 2]);
                acc[4 * j + 3] = fmaf(wv.w, t, acc[4 * j + 3]);
            }
        }
        #pragma unroll
        for (int j = 0; j < 40; j++) ssum[j] += fmaxf(acc[j], 0.f);
    }

    // ---- x3 = relu(W3 @ ssum + b3); means/logvar accumulated on the fly
    float m[16];
    {
        const float4* bmv4 = (const float4*)&sw[L_BMV];
        #pragma unroll
        for (int k = 0; k < 4; k++) {
            float4 bv4 = bmv4[k];
            m[4 * k] = bv4.x; m[4 * k + 1] = bv4.y;
            m[4 * k + 2] = bv4.z; m[4 * k + 3] = bv4.w;
        }
    }
    #pragma unroll 2
    for (int o = 0; o < 128; o++) {
        float t = sw[L_B3 + o];
        const float4* w3r = (const float4*)&sw[L_W3 + o * 40];
        #pragma unroll
        for (int j = 0; j < 10; j++) {
            float4 wv = w3r[j];
            t = fmaf(wv.x, ssum[4 * j], t);
            t = fmaf(wv.y, ssum[4 * j + 1], t);
            t = fmaf(wv.z, ssum[4 * j + 2], t);
            t = fmaf(wv.w, ssum[4 * j + 3], t);
        }
        t = fmaxf(t, 0.f);
        const float4* mvr = (const float4*)&sw[L_MV + o * 16];
        #pragma unroll
        for (int k = 0; k < 4; k++) {
            float4 wv = mvr[k];
            m[4 * k]     = fmaf(wv.x, t, m[4 * k]);
            m[4 * k + 1] = fmaf(wv.y, t, m[4 * k + 1]);
            m[4 * k + 2] = fmaf(wv.z, t, m[4 * k + 2]);
            m[4 * k + 3] = fmaf(wv.w, t, m[4 * k + 3]);
        }
    }

    // ---- reparameterization (eps loaded late to reduce liveness)
    const float4* epsq = (const float4*)eps;
    float4 e0 = epsq[2 * b];
    float4 e1 = epsq[2 * b + 1];
    float epsv[8] = { e0.x, e0.y, e0.z, e0.w, e1.x, e1.y, e1.z, e1.w };
    float zf[8];
    #pragma unroll
    for (int k = 0; k < 8; k++)
        zf[k] = fmaf(epsv[k], __expf(0.5f * m[8 + k]), m[k]);

    // ---- decoder
    float icv[12];
    load12(ic, b, icv);
    float h[32];
    {
        const float4* d1c4 = (const float4*)&sw[L_D1C];
        #pragma unroll
        for (int k = 0; k < 8; k++) {
            float4 c4 = d1c4[k];
            h[4 * k] = c4.x; h[4 * k + 1] = c4.y;
            h[4 * k + 2] = c4.z; h[4 * k + 3] = c4.w;
        }
    }
    #pragma unroll
    for (int j = 0; j < 20; j++) {
        const float xj = (j < 12) ? icv[j] : zf[j - 12];
        const float4* d1r = (const float4*)&sw[L_D1T + j * 32];
        #pragma unroll
        for (int k = 0; k < 8; k++) {
            float4 wv = d1r[k];
            h[4 * k]     = fmaf(wv.x, xj, h[4 * k]);
            h[4 * k + 1] = fmaf(wv.y, xj, h[4 * k + 1]);
            h[4 * k + 2] = fmaf(wv.z, xj, h[4 * k + 2]);
            h[4 * k + 3] = fmaf(wv.w, xj, h[4 * k + 3]);
        }
    }
    #pragma unroll
    for (int o = 0; o < 32; o++) h[o] = fmaxf(h[o], 0.f);

    float rec[12];
    #pragma unroll
    for (int rr = 0; rr < 12; rr++) {
        float a = sw[L_BD2 + rr];
        const float4* d2r = (const float4*)&sw[L_D2 + rr * 32];
        #pragma unroll
        for (int k = 0; k < 8; k++) {
            float4 wv = d2r[k];
            a = fmaf(wv.x, h[4 * k], a);
            a = fmaf(wv.y, h[4 * k + 1], a);
            a = fmaf(wv.z, h[4 * k + 2], a);
            a = fmaf(wv.w, h[4 * k + 3], a);
        }
        rec[rr] = 1.f / (1.f + __expf(-a));
    }

    // ---- fp32 stores: recon [B,12] | means [B,8] | logvar [B,8] | z [B,8]
    float4* out4 = (float4*)out;
    out4[b * 3 + 0] = make_float4(rec[0], rec[1], rec[2], rec[3]);
    out4[b * 3 + 1] = make_float4(rec[4], rec[5], rec[6], rec[7]);
    out4[b * 3 + 2] = make_float4(rec[8], rec[9], rec[10], rec[11]);

    const long mbase = (long)B * 3 + 2 * b;
    const long lbase = (long)B * 5 + 2 * b;
    const long zbase = (long)B * 7 + 2 * b;
    out4[mbase + 0] = make_float4(m[0], m[1], m[2], m[3]);
    out4[mbase + 1] = make_float4(m[4], m[5], m[6], m[7]);
    out4[lbase + 0] = make_float4(m[8], m[9], m[10], m[11]);
    out4[lbase + 1] = make_float4(m[12], m[13], m[14], m[15]);
    out4[zbase + 0] = make_float4(zf[0], zf[1], zf[2], zf[3]);
    out4[zbase + 1] = make_float4(zf[4], zf[5], zf[6], zf[7]);
}

extern "C" void kernel_launch(void* const* d_in, const int* in_sizes, int n_in,
                              void* d_out, int out_size, void* d_ws, size_t ws_size,
                              hipStream_t stream) {
    const float* ic  = (const float*)d_in[0];   // initial_c [B,30]
    // d_in[1] initial_s — unused by the reference
    const float* cc  = (const float*)d_in[2];   // current_c [B,30]
    const float* eps = (const float*)d_in[3];   // eps [B,8]

    const int B = in_sizes[3] / 8;              // 262144
    const int nblocks = B / TPB;                // 512

    vae_fused<<<nblocks, TPB, 0, stream>>>(
        ic, cc, eps,
        (const float*)d_in[4],  (const float*)d_in[5],
        (const float*)d_in[6],  (const float*)d_in[7],
        (const float*)d_in[8],  (const float*)d_in[9],
        (const float*)d_in[10], (const float*)d_in[11],
        (const float*)d_in[12], (const float*)d_in[13],
        (const float*)d_in[14], (const float*)d_in[15],
        (const float*)d_in[16], (const float*)d_in[17],
        (float*)d_out, B);
}

// Round 6
// 202.714 us; speedup vs baseline: 2.3948x; 1.9957x over previous
//
#include <hip/hip_runtime.h>
#include <hip/hip_bf16.h>

#define TPB 256

typedef __attribute__((ext_vector_type(8))) short short8;
typedef __attribute__((ext_vector_type(4))) float f32x4;

// ---- weight image byte offsets (d_ws; first G_LCOPY bytes mirrored in LDS) ----
#define G_W2F   0        // [t=3][s=4][lane=64][j=8] bf16  12288
#define G_MVF   12288    // [s=4][64][8] bf16               4096
#define G_D1F   16384    // [t=2][64][8] bf16               2048
#define G_D2F   18432    // [64][8] bf16                    1024
#define G_CEAB  19456    // [e=4][o=128] bf16x4 {ce,a0,a1,a2} 4096
#define G_B2P   23552    // [48] f32 (pad 0)
#define G_B3    23744    // [128] f32
#define G_BMV   24256    // [16] f32 (bm|bv)
#define G_D1C   24320    // [32] f32 (Wd1 col0 + bd1)
#define G_BD2   24448    // [16] f32 (pad 0)
#define G_LCOPY 24512
#define G_W3F   24512    // [nt=8][s=2][64][8] bf16        16384 (read from global/L2)
#define G_END   40896

// ---- per-wave LDS region ----
#define PW_SZ   6912
#define PW_SWC  0        // [16][12] f32 (768)
#define PW_SIC  768      // [16][32] bf16 (1024) decoder input k-major per row
#define PW_ST   1792     // [16][64] bf16 (2048) -- union with X3T (sequential use)
#define PW_X3T  1792     // [16][128] bf16 (4096)
#define PW_MLV  5888     // [16][16] f32 (1024) -- aliased by HT (sequential use)
#define PW_HT   5888     // [16][32] bf16 (1024)
#define LDS_TOT (G_LCOPY + 4 * PW_SZ)   // 52160 B -> 3 blocks/CU

__device__ __forceinline__ unsigned short f2bf(float f) {
    unsigned int u = __float_as_uint(f);
    unsigned int r = u + 0x7fffu + ((u >> 16) & 1u);   // RNE
    return (unsigned short)(r >> 16);
}
__device__ __forceinline__ float lo16(unsigned int d) { return __uint_as_float(d << 16); }
__device__ __forceinline__ float hi16(unsigned int d) { return __uint_as_float(d & 0xffff0000u); }
__device__ __forceinline__ unsigned int pk(float a, float b) {
    __hip_bfloat162 h = __float22bfloat162_rn(make_float2(a, b));
    unsigned int u; __builtin_memcpy(&u, &h, 4); return u;
}
__device__ __forceinline__ unsigned short bfbits(float v) {
    return (unsigned short)(pk(v, v) & 0xffffu);
}

__global__ void prep_kernel(
    const float* __restrict__ W1, const float* __restrict__ b1,
    const float* __restrict__ W2, const float* __restrict__ b2,
    const float* __restrict__ W3, const float* __restrict__ b3,
    const float* __restrict__ Wm, const float* __restrict__ bm,
    const float* __restrict__ Wv, const float* __restrict__ bv,
    const float* __restrict__ Wd1, const float* __restrict__ bd1,
    const float* __restrict__ Wd2, const float* __restrict__ bd2,
    unsigned char* __restrict__ ws)
{
    const int t0 = threadIdx.x;
    unsigned short* w2f = (unsigned short*)(ws + G_W2F);
    for (int i = t0; i < 6144; i += TPB) {          // B[k][n] = W2[n][k]
        int j = i & 7, lane = (i >> 3) & 63, ts = i >> 9;
        int tt = ts >> 2, s = ts & 3;
        int n = 16 * tt + (lane & 15), k = 32 * s + 8 * (lane >> 4) + j;
        w2f[i] = (n < 39) ? f2bf(W2[n * 128 + k]) : 0;
    }
    unsigned short* w3f = (unsigned short*)(ws + G_W3F);
    for (int i = t0; i < 8192; i += TPB) {          // B[k][n] = W3[n][k]
        int j = i & 7, lane = (i >> 3) & 63, ns = i >> 9;
        int nt = ns >> 1, s = ns & 1;
        int n = 16 * nt + (lane & 15), k = 32 * s + 8 * (lane >> 4) + j;
        w3f[i] = (k < 39) ? f2bf(W3[n * 39 + k]) : 0;
    }
    unsigned short* mvf = (unsigned short*)(ws + G_MVF);
    for (int i = t0; i < 2048; i += TPB) {          // n<8: Wm, n>=8: Wv
        int j = i & 7, lane = (i >> 3) & 63, s = i >> 9;
        int n = lane & 15, k = 32 * s + 8 * (lane >> 4) + j;
        mvf[i] = f2bf(n < 8 ? Wm[n * 128 + k] : Wv[(n - 8) * 128 + k]);
    }
    unsigned short* d1f = (unsigned short*)(ws + G_D1F);
    for (int i = t0; i < 1024; i += TPB) {          // k<20 -> Wd1[n][5+k]
        int j = i & 7, lane = (i >> 3) & 63, tt = i >> 9;
        int n = 16 * tt + (lane & 15), k = 8 * (lane >> 4) + j;
        d1f[i] = (k < 20) ? f2bf(Wd1[n * 25 + 5 + k]) : 0;
    }
    unsigned short* d2f = (unsigned short*)(ws + G_D2F);
    for (int i = t0; i < 512; i += TPB) {
        int j = i & 7, lane = i >> 3;
        int n = lane & 15, k = 8 * (lane >> 4) + j;
        d2f[i] = (n < 12) ? f2bf(Wd2[n * 32 + k]) : 0;
    }
    unsigned short* ceab = (unsigned short*)(ws + G_CEAB);
    for (int i = t0; i < 2048; i += TPB) {          // {ce,a0,a1,a2} per (e,o)
        int c = i & 3, o = (i >> 2) & 127, e = i >> 9;
        float v = (c == 0) ? (W1[o * 13 + 0] + W1[o * 13 + 6 + e] + b1[o])
                           : W1[o * 13 + 9 + c];
        ceab[i] = f2bf(v);
    }
    float* fb = (float*)(ws + G_B2P);
    for (int i = t0; i < 48; i += TPB) fb[i] = (i < 39) ? b2[i] : 0.f;
    fb = (float*)(ws + G_B3);
    for (int i = t0; i < 128; i += TPB) fb[i] = b3[i];
    fb = (float*)(ws + G_BMV);
    for (int i = t0; i < 16; i += TPB) fb[i] = (i < 8) ? bm[i] : bv[i - 8];
    fb = (float*)(ws + G_D1C);
    for (int i = t0; i < 32; i += TPB) fb[i] = Wd1[i * 25 + 0] + bd1[i];
    fb = (float*)(ws + G_BD2);
    for (int i = t0; i < 16; i += TPB) fb[i] = (i < 12) ? bd2[i] : 0.f;
}

union S8 { short8 v; uint4 u; };

__global__ __launch_bounds__(TPB, 2) void vae_mfma(
    const float* __restrict__ ic, const float* __restrict__ cc,
    const float* __restrict__ eps,
    const unsigned char* __restrict__ ws,
    float* __restrict__ out, int B)
{
    __shared__ __attribute__((aligned(16))) unsigned char lds[LDS_TOT];
    const int tid = threadIdx.x;

    {   // weight image -> LDS (linear, coalesced; L2-hot after first blocks)
        const uint4* src = (const uint4*)ws;
        uint4* dst = (uint4*)lds;
        #pragma unroll
        for (int it = 0; it < 6; it++) {
            int idx = it * TPB + tid;
            if (idx < G_LCOPY / 16) dst[idx] = src[idx];
        }
    }
    __syncthreads();

    const int lane = tid & 63, w = tid >> 6;
    const int quad = lane >> 4, n16 = lane & 15;
    const long rb = ((long)blockIdx.x * 4 + w) * 16;
    unsigned char* pw = lds + G_LCOPY + w * PW_SZ;

    // ---- stage cc (fp32, for x1 p's) and ic (bf16, decoder k=0..11) ----
    {
        int r = lane >> 2, g = lane & 3;
        long R = rb + r;
        const int cbase[4] = {0, 2, 10, 12};
        const int csing[4] = {14, 18, 22, 26};
        const float* crow = cc + R * 30;
        const float* irow = ic + R * 30;
        float2 cp = *(const float2*)(crow + cbase[g]);
        float  cs = crow[csing[g]];
        float2 ip = *(const float2*)(irow + cbase[g]);
        float  is = irow[csing[g]];
        float* swc = (float*)(pw + PW_SWC);
        *(float2*)(swc + r * 12 + 2 * g) = cp;
        swc[r * 12 + 8 + g] = cs;
        unsigned short* sic = (unsigned short*)(pw + PW_SIC);
        *(unsigned int*)(sic + r * 32 + 2 * g) = pk(ip.x, ip.y);
        sic[r * 32 + 8 + g] = bfbits(is);
        if (g < 3) *(unsigned long long*)(sic + r * 32 + 20 + 4 * g) = 0ull; // k=20..31
        unsigned short* st = (unsigned short*)(pw + PW_ST);
        *(unsigned long long*)(st + r * 64 + 48 + 4 * g) = 0ull;            // cols 48..63
    }

    // ---- W2 B-fragments + biases ----
    short8 B2[12];
    #pragma unroll
    for (int ts = 0; ts < 12; ts++) {
        S8 x; x.u = *(const uint4*)(lds + G_W2F + (ts * 64 + lane) * 16);
        B2[ts] = x.v;
    }
    const float b2v0 = *(const float*)(lds + G_B2P + n16 * 4);
    const float b2v1 = *(const float*)(lds + G_B2P + (16 + n16) * 4);
    const float b2v2 = *(const float*)(lds + G_B2P + (32 + n16) * 4);

    f32x4 ss0 = {0,0,0,0}, ss1 = {0,0,0,0}, ss2 = {0,0,0,0};
    const float* swc = (const float*)(pw + PW_SWC);

    // ---- message MLP: x1 built in A-frag layout, L2 via MFMA, relu-sum over edges
    #pragma unroll
    for (int e = 0; e < 4; e++) {
        float p0 = swc[n16 * 12 + e];
        float p1 = swc[n16 * 12 + 4 + e];
        float p2 = swc[n16 * 12 + 8 + e];
        f32x4 c0 = {b2v0, b2v0, b2v0, b2v0};
        f32x4 c1 = {b2v1, b2v1, b2v1, b2v1};
        f32x4 c2 = {b2v2, b2v2, b2v2, b2v2};
        #pragma unroll
        for (int s = 0; s < 4; s++) {
            const uint4* cea = (const uint4*)(lds + G_CEAB + (e * 128 + s * 32 + quad * 8) * 8);
            float xf[8];
            #pragma unroll
            for (int u = 0; u < 4; u++) {
                uint4 q = cea[u];
                float t = lo16(q.x);
                t = fmaf(hi16(q.x), p0, t);
                t = fmaf(lo16(q.y), p1, t);
                t = fmaf(hi16(q.y), p2, t);
                xf[2 * u] = fmaxf(t, 0.f);
                t = lo16(q.z);
                t = fmaf(hi16(q.z), p0, t);
                t = fmaf(lo16(q.w), p1, t);
                t = fmaf(hi16(q.w), p2, t);
                xf[2 * u + 1] = fmaxf(t, 0.f);
            }
            S8 a;
            a.u.x = pk(xf[0], xf[1]); a.u.y = pk(xf[2], xf[3]);
            a.u.z = pk(xf[4], xf[5]); a.u.w = pk(xf[6], xf[7]);
            c0 = __builtin_amdgcn_mfma_f32_16x16x32_bf16(a.v, B2[s],     c0, 0, 0, 0);
            c1 = __builtin_amdgcn_mfma_f32_16x16x32_bf16(a.v, B2[4 + s], c1, 0, 0, 0);
            c2 = __builtin_amdgcn_mfma_f32_16x16x32_bf16(a.v, B2[8 + s], c2, 0, 0, 0);
        }
        #pragma unroll
        for (int r = 0; r < 4; r++) {
            ss0[r] += fmaxf(c0[r], 0.f);
            ss1[r] += fmaxf(c1[r], 0.f);
            ss2[r] += fmaxf(c2[r], 0.f);
        }
    }

    // ---- relayout s: C-layout -> [row][k] bf16 tile ----
    unsigned short* st = (unsigned short*)(pw + PW_ST);
    #pragma unroll
    for (int r = 0; r < 4; r++) {
        int row = quad * 4 + r;
        st[row * 64 + n16]      = bfbits(ss0[r]);
        st[row * 64 + 16 + n16] = bfbits(ss1[r]);
        st[row * 64 + 32 + n16] = bfbits(ss2[r]);   // cols 39..47 are exact zeros
    }

    // ---- L3: A from st, B streamed from global (L2-resident) ----
    S8 A30, A31;
    A30.u = *(const uint4*)(st + n16 * 64 + quad * 8);
    A31.u = *(const uint4*)(st + n16 * 64 + 32 + quad * 8);
    const uint4* w3g = (const uint4*)(ws + G_W3F);
    unsigned short* x3t = (unsigned short*)(pw + PW_X3T);
    const float* b3p = (const float*)(lds + G_B3);
    #pragma unroll
    for (int nt = 0; nt < 8; nt++) {
        float bb = b3p[nt * 16 + n16];
        f32x4 c = {bb, bb, bb, bb};
        S8 bf0, bf1;
        bf0.u = w3g[(nt * 2 + 0) * 64 + lane];
        bf1.u = w3g[(nt * 2 + 1) * 64 + lane];
        c = __builtin_amdgcn_mfma_f32_16x16x32_bf16(A30.v, bf0.v, c, 0, 0, 0);
        c = __builtin_amdgcn_mfma_f32_16x16x32_bf16(A31.v, bf1.v, c, 0, 0, 0);
        #pragma unroll
        for (int r = 0; r < 4; r++)
            x3t[(quad * 4 + r) * 128 + nt * 16 + n16] = bfbits(fmaxf(c[r], 0.f));
    }

    // ---- heads: means|logvar (N=16) ----
    S8 Ah0, Ah1, Ah2, Ah3;
    Ah0.u = *(const uint4*)(x3t + n16 * 128 + 0  + quad * 8);
    Ah1.u = *(const uint4*)(x3t + n16 * 128 + 32 + quad * 8);
    Ah2.u = *(const uint4*)(x3t + n16 * 128 + 64 + quad * 8);
    Ah3.u = *(const uint4*)(x3t + n16 * 128 + 96 + quad * 8);
    float bmvv = *(const float*)(lds + G_BMV + n16 * 4);
    f32x4 cm = {bmvv, bmvv, bmvv, bmvv};
    {
        S8 bm0; bm0.u = *(const uint4*)(lds + G_MVF + (0 * 64 + lane) * 16);
        cm = __builtin_amdgcn_mfma_f32_16x16x32_bf16(Ah0.v, bm0.v, cm, 0, 0, 0);
        S8 bm1; bm1.u = *(const uint4*)(lds + G_MVF + (1 * 64 + lane) * 16);
        cm = __builtin_amdgcn_mfma_f32_16x16x32_bf16(Ah1.v, bm1.v, cm, 0, 0, 0);
        S8 bm2; bm2.u = *(const uint4*)(lds + G_MVF + (2 * 64 + lane) * 16);
        cm = __builtin_amdgcn_mfma_f32_16x16x32_bf16(Ah2.v, bm2.v, cm, 0, 0, 0);
        S8 bm3; bm3.u = *(const uint4*)(lds + G_MVF + (3 * 64 + lane) * 16);
        cm = __builtin_amdgcn_mfma_f32_16x16x32_bf16(Ah3.v, bm3.v, cm, 0, 0, 0);
    }
    float* mlv = (float*)(pw + PW_MLV);
    #pragma unroll
    for (int r = 0; r < 4; r++) mlv[(quad * 4 + r) * 16 + n16] = cm[r];

    // ---- reparameterization + means/logvar/z outputs ----
    {
        int r = lane >> 2, q2 = (lane & 3) * 2;
        long R = rb + r;
        const float* mrow = mlv + r * 16;
        float2 mn = *(const float2*)(mrow + q2);
        float2 lv = *(const float2*)(mrow + 8 + q2);
        float2 ev = *(const float2*)(eps + R * 8 + q2);
        float z0 = fmaf(ev.x, __expf(0.5f * lv.x), mn.x);
        float z1 = fmaf(ev.y, __expf(0.5f * lv.y), mn.y);
        *(float2*)(out + (long)B * 12 + R * 8 + q2) = mn;
        *(float2*)(out + (long)B * 20 + R * 8 + q2) = lv;
        *(float2*)(out + (long)B * 28 + R * 8 + q2) = make_float2(z0, z1);
        unsigned short* sic = (unsigned short*)(pw + PW_SIC);
        *(unsigned int*)(sic + r * 32 + 12 + q2) = pk(z0, z1);   // decoder k=12..19
    }

    // ---- decoder layer 1 (N=32, K=32) ----
    S8 Ad;
    Ad.u = *(const uint4*)((const unsigned short*)(pw + PW_SIC) + n16 * 32 + quad * 8);
    unsigned short* ht = (unsigned short*)(pw + PW_HT);
    #pragma unroll
    for (int t = 0; t < 2; t++) {
        float dc = *(const float*)(lds + G_D1C + (t * 16 + n16) * 4);
        f32x4 c = {dc, dc, dc, dc};
        S8 bd; bd.u = *(const uint4*)(lds + G_D1F + (t * 64 + lane) * 16);
        c = __builtin_amdgcn_mfma_f32_16x16x32_bf16(Ad.v, bd.v, c, 0, 0, 0);
        #pragma unroll
        for (int r = 0; r < 4; r++)
            ht[(quad * 4 + r) * 32 + t * 16 + n16] = bfbits(fmaxf(c[r], 0.f));
    }

    // ---- decoder layer 2 (N=16, K=32) + sigmoid + recon store ----
    S8 Ah2d; Ah2d.u = *(const uint4*)(ht + n16 * 32 + quad * 8);
    float bd2v = *(const float*)(lds + G_BD2 + n16 * 4);
    f32x4 cr = {bd2v, bd2v, bd2v, bd2v};
    S8 b2d; b2d.u = *(const uint4*)(lds + G_D2F + lane * 16);
    cr = __builtin_amdgcn_mfma_f32_16x16x32_bf16(Ah2d.v, b2d.v, cr, 0, 0, 0);
    if (n16 < 12) {
        #pragma unroll
        for (int r = 0; r < 4; r++)
            out[(rb + quad * 4 + r) * 12 + n16] = 1.f / (1.f + __expf(-cr[r]));
    }
}

extern "C" void kernel_launch(void* const* d_in, const int* in_sizes, int n_in,
                              void* d_out, int out_size, void* d_ws, size_t ws_size,
                              hipStream_t stream) {
    const float* ic  = (const float*)d_in[0];   // initial_c [B,30]
    const float* cc  = (const float*)d_in[2];   // current_c [B,30]
    const float* eps = (const float*)d_in[3];   // eps [B,8]

    const int B = in_sizes[3] / 8;              // 262144
    const int nblocks = B / 64;                 // 4096

    prep_kernel<<<1, TPB, 0, stream>>>(
        (const float*)d_in[4],  (const float*)d_in[5],
        (const float*)d_in[6],  (const float*)d_in[7],
        (const float*)d_in[8],  (const float*)d_in[9],
        (const float*)d_in[10], (const float*)d_in[11],
        (const float*)d_in[12], (const float*)d_in[13],
        (const float*)d_in[14], (const float*)d_in[15],
        (const float*)d_in[16], (const float*)d_in[17],
        (unsigned char*)d_ws);
    vae_mfma<<<nblocks, TPB, 0, stream>>>(
        ic, cc, eps, (const unsigned char*)d_ws, (float*)d_out, B);
}

// Round 7
// 195.425 us; speedup vs baseline: 2.4842x; 1.0373x over previous
//
#include <hip/hip_runtime.h>
#include <hip/hip_bf16.h>

#define TPB 256
#define PREP_BLOCKS 64

typedef __attribute__((ext_vector_type(8))) short short8;
typedef __attribute__((ext_vector_type(4))) float f32x4;

// ---- weight image byte offsets (d_ws; first G_LCOPY bytes mirrored in LDS) ----
#define G_W2F   0        // [t=3][s=4][lane=64][j=8] bf16  12288
#define G_MVF   12288    // [s=4][64][8] bf16               4096
#define G_D1F   16384    // [t=2][64][8] bf16               2048
#define G_D2F   18432    // [64][8] bf16                    1024
#define G_CEAB  19456    // [e=4][n=128][4] bf16 {a0,a1,a2,ce} 4096
#define G_B2P   23552    // [48] f32 (pad 0)
#define G_B3    23744    // [128] f32
#define G_BMV   24256    // [16] f32 (bm|bv)
#define G_D1C   24320    // [32] f32 (Wd1 col0 + bd1)
#define G_BD2   24448    // [16] f32 (pad 0)
#define G_LCOPY 24512
#define G_W3F   24512    // [nt=8][s=2][64][8] bf16        16384 (read from global/L2)
#define G_END   40896

// ---- per-wave LDS region (strides padded for bank spread, 16B-aligned rows) ----
#define PW_SWC  0        // [16][12] f32 (768)
#define PW_SIC  768      // [16][40] bf16 (1280) decoder input, k-major per row
#define PW_ST   2048     // [16][72] bf16 (2304) s-tile (cols 0..63 used)
#define PW_BUF  4352     // [16][136] bf16 (4352) x1-tile per edge / x3-tile
#define PW_MH   8704     // union: [16][18] f32 mlv (1152) | [16][40] bf16 ht (1280)
#define PW_SZ   9984
#define LDS_TOT (G_LCOPY + 4 * PW_SZ)   // 64448 B

__device__ __forceinline__ unsigned short f2bf(float f) {
    unsigned int u = __float_as_uint(f);
    unsigned int r = u + 0x7fffu + ((u >> 16) & 1u);   // RNE
    return (unsigned short)(r >> 16);
}
__device__ __forceinline__ unsigned int pk(float a, float b) {
    __hip_bfloat162 h = __float22bfloat162_rn(make_float2(a, b));
    unsigned int u; __builtin_memcpy(&u, &h, 4); return u;
}
__device__ __forceinline__ unsigned short bfbits(float v) {
    return (unsigned short)(pk(v, v) & 0xffffu);
}

__global__ void prep_kernel(
    const float* __restrict__ W1, const float* __restrict__ b1,
    const float* __restrict__ W2, const float* __restrict__ b2,
    const float* __restrict__ W3, const float* __restrict__ b3,
    const float* __restrict__ Wm, const float* __restrict__ bm,
    const float* __restrict__ Wv, const float* __restrict__ bv,
    const float* __restrict__ Wd1, const float* __restrict__ bd1,
    const float* __restrict__ Wd2, const float* __restrict__ bd2,
    unsigned char* __restrict__ ws)
{
    const int g0 = blockIdx.x * TPB + threadIdx.x;
    const int gs = gridDim.x * TPB;
    unsigned short* w2f = (unsigned short*)(ws + G_W2F);
    for (int i = g0; i < 6144; i += gs) {           // B[k][n] = W2[n][k]
        int j = i & 7, lane = (i >> 3) & 63, ts = i >> 9;
        int tt = ts >> 2, s = ts & 3;
        int n = 16 * tt + (lane & 15), k = 32 * s + 8 * (lane >> 4) + j;
        w2f[i] = (n < 39) ? f2bf(W2[n * 128 + k]) : 0;
    }
    unsigned short* w3f = (unsigned short*)(ws + G_W3F);
    for (int i = g0; i < 8192; i += gs) {           // B[k][n] = W3[n][k]
        int j = i & 7, lane = (i >> 3) & 63, ns = i >> 9;
        int nt = ns >> 1, s = ns & 1;
        int n = 16 * nt + (lane & 15), k = 32 * s + 8 * (lane >> 4) + j;
        w3f[i] = (k < 39) ? f2bf(W3[n * 39 + k]) : 0;
    }
    unsigned short* mvf = (unsigned short*)(ws + G_MVF);
    for (int i = g0; i < 2048; i += gs) {           // n<8: Wm, n>=8: Wv
        int j = i & 7, lane = (i >> 3) & 63, s = i >> 9;
        int n = lane & 15, k = 32 * s + 8 * (lane >> 4) + j;
        mvf[i] = f2bf(n < 8 ? Wm[n * 128 + k] : Wv[(n - 8) * 128 + k]);
    }
    unsigned short* d1f = (unsigned short*)(ws + G_D1F);
    for (int i = g0; i < 1024; i += gs) {           // k<20 -> Wd1[n][5+k]
        int j = i & 7, lane = (i >> 3) & 63, tt = i >> 9;
        int n = 16 * tt + (lane & 15), k = 8 * (lane >> 4) + j;
        d1f[i] = (k < 20) ? f2bf(Wd1[n * 25 + 5 + k]) : 0;
    }
    unsigned short* d2f = (unsigned short*)(ws + G_D2F);
    for (int i = g0; i < 512; i += gs) {
        int j = i & 7, lane = i >> 3;
        int n = lane & 15, k = 8 * (lane >> 4) + j;
        d2f[i] = (n < 12) ? f2bf(Wd2[n * 32 + k]) : 0;
    }
    unsigned short* ceab = (unsigned short*)(ws + G_CEAB);
    for (int i = g0; i < 2048; i += gs) {           // [e][n][4] {a0,a1,a2,ce}
        int c = i & 3, n = (i >> 2) & 127, e = i >> 9;
        float v = (c < 3) ? W1[n * 13 + 10 + c]
                          : (W1[n * 13 + 0] + W1[n * 13 + 6 + e] + b1[n]);
        ceab[i] = f2bf(v);
    }
    float* fb = (float*)(ws + G_B2P);
    for (int i = g0; i < 48; i += gs) fb[i] = (i < 39) ? b2[i] : 0.f;
    fb = (float*)(ws + G_B3);
    for (int i = g0; i < 128; i += gs) fb[i] = b3[i];
    fb = (float*)(ws + G_BMV);
    for (int i = g0; i < 16; i += gs) fb[i] = (i < 8) ? bm[i] : bv[i - 8];
    fb = (float*)(ws + G_D1C);
    for (int i = g0; i < 32; i += gs) fb[i] = Wd1[i * 25 + 0] + bd1[i];
    fb = (float*)(ws + G_BD2);
    for (int i = g0; i < 16; i += gs) fb[i] = (i < 12) ? bd2[i] : 0.f;
}

union S8 { short8 v; uint4 u; };

__global__ __launch_bounds__(TPB, 2) void vae_mfma(
    const float* __restrict__ ic, const float* __restrict__ cc,
    const float* __restrict__ eps,
    const unsigned char* __restrict__ ws,
    float* __restrict__ out, int B)
{
    __shared__ __attribute__((aligned(16))) unsigned char lds[LDS_TOT];
    const int tid = threadIdx.x;

    {   // weight image -> LDS (linear, coalesced; L2-hot)
        const uint4* src = (const uint4*)ws;
        uint4* dst = (uint4*)lds;
        #pragma unroll
        for (int it = 0; it < 6; it++) {
            int idx = it * TPB + tid;
            if (idx < G_LCOPY / 16) dst[idx] = src[idx];
        }
    }
    __syncthreads();

    const int lane = tid & 63, w = tid >> 6;
    const int quad = lane >> 4, n16 = lane & 15;
    const bool q0 = (quad == 0);
    const long rb = ((long)blockIdx.x * 4 + w) * 16;
    unsigned char* pw = lds + G_LCOPY + w * PW_SZ;

    // ---- stage cc (fp32 p's) and ic (bf16 decoder k=0..11); zero pads ----
    {
        int r = lane >> 2, g = lane & 3;
        long R = rb + r;
        const int cbase[4] = {0, 2, 10, 12};
        const int csing[4] = {14, 18, 22, 26};
        const float* crow = cc + R * 30;
        const float* irow = ic + R * 30;
        float2 cp = *(const float2*)(crow + cbase[g]);
        float  cs = crow[csing[g]];
        float2 ip = *(const float2*)(irow + cbase[g]);
        float  is = irow[csing[g]];
        float* swc = (float*)(pw + PW_SWC);
        *(float2*)(swc + r * 12 + 2 * g) = cp;
        swc[r * 12 + 8 + g] = cs;
        unsigned short* sic = (unsigned short*)(pw + PW_SIC);
        *(unsigned int*)(sic + r * 40 + 2 * g) = pk(ip.x, ip.y);
        sic[r * 40 + 8 + g] = bfbits(is);
        if (g < 3) *(unsigned long long*)(sic + r * 40 + 20 + 4 * g) = 0ull; // k=20..31
        unsigned short* st = (unsigned short*)(pw + PW_ST);
        *(unsigned long long*)(st + r * 72 + 48 + 4 * g) = 0ull;             // cols 48..63
    }

    // ---- W2 B-fragments + biases ----
    short8 B2[12];
    #pragma unroll
    for (int ts = 0; ts < 12; ts++) {
        S8 x; x.u = *(const uint4*)(lds + G_W2F + (ts * 64 + lane) * 16);
        B2[ts] = x.v;
    }
    const float b2v0 = *(const float*)(lds + G_B2P + n16 * 4);
    const float b2v1 = *(const float*)(lds + G_B2P + (16 + n16) * 4);
    const float b2v2 = *(const float*)(lds + G_B2P + (32 + n16) * 4);

    // p-values for this lane's row (n16)
    float pa[4], pb[4], pc[4];
    {
        const float* swcr = (const float*)(pw + PW_SWC) + n16 * 12;
        float4 t0 = *(const float4*)(swcr);
        float4 t1 = *(const float4*)(swcr + 4);
        float4 t2 = *(const float4*)(swcr + 8);
        pa[0] = t0.x; pa[1] = t0.y; pa[2] = t0.z; pa[3] = t0.w;
        pb[0] = t1.x; pb[1] = t1.y; pb[2] = t1.z; pb[3] = t1.w;
        pc[0] = t2.x; pc[1] = t2.y; pc[2] = t2.z; pc[3] = t2.w;
    }

    f32x4 ss0 = {0,0,0,0}, ss1 = {0,0,0,0}, ss2 = {0,0,0,0};
    unsigned short* x1t = (unsigned short*)(pw + PW_BUF);

    // ---- message MLP: L1 via MFMA (bias in k=3), relayout, L2 via MFMA ----
    #pragma unroll
    for (int e = 0; e < 4; e++) {
        S8 a1;
        a1.u.x = q0 ? pk(pa[e], pb[e]) : 0u;
        a1.u.y = q0 ? pk(pc[e], 1.0f) : 0u;
        a1.u.z = 0u; a1.u.w = 0u;
        const unsigned long long* cb =
            (const unsigned long long*)(lds + G_CEAB + e * 1024);
        f32x4 cr[8];
        #pragma unroll
        for (int nt = 0; nt < 8; nt++) {
            unsigned long long bw = cb[nt * 16 + n16];
            S8 bf;
            bf.u.x = q0 ? (unsigned int)bw : 0u;
            bf.u.y = q0 ? (unsigned int)(bw >> 32) : 0u;
            bf.u.z = 0u; bf.u.w = 0u;
            f32x4 z = {0, 0, 0, 0};
            cr[nt] = __builtin_amdgcn_mfma_f32_16x16x32_bf16(a1.v, bf.v, z, 0, 0, 0);
        }
        #pragma unroll
        for (int nt = 0; nt < 8; nt++) {
            #pragma unroll
            for (int r = 0; r < 4; r++)
                x1t[(quad * 4 + r) * 136 + nt * 16 + n16] = bfbits(fmaxf(cr[nt][r], 0.f));
        }
        f32x4 c0 = {b2v0, b2v0, b2v0, b2v0};
        f32x4 c1 = {b2v1, b2v1, b2v1, b2v1};
        f32x4 c2 = {b2v2, b2v2, b2v2, b2v2};
        #pragma unroll
        for (int s = 0; s < 4; s++) {
            S8 a2; a2.u = *(const uint4*)(x1t + n16 * 136 + s * 32 + quad * 8);
            c0 = __builtin_amdgcn_mfma_f32_16x16x32_bf16(a2.v, B2[s],     c0, 0, 0, 0);
            c1 = __builtin_amdgcn_mfma_f32_16x16x32_bf16(a2.v, B2[4 + s], c1, 0, 0, 0);
            c2 = __builtin_amdgcn_mfma_f32_16x16x32_bf16(a2.v, B2[8 + s], c2, 0, 0, 0);
        }
        #pragma unroll
        for (int r = 0; r < 4; r++) {
            ss0[r] += fmaxf(c0[r], 0.f);
            ss1[r] += fmaxf(c1[r], 0.f);
            ss2[r] += fmaxf(c2[r], 0.f);
        }
    }

    // ---- relayout s: C-layout -> [row][k] bf16 (stride 72) ----
    unsigned short* st = (unsigned short*)(pw + PW_ST);
    #pragma unroll
    for (int r = 0; r < 4; r++) {
        int row = quad * 4 + r;
        st[row * 72 + n16]      = bfbits(ss0[r]);
        st[row * 72 + 16 + n16] = bfbits(ss1[r]);
        st[row * 72 + 32 + n16] = bfbits(ss2[r]);   // cols 39..47 exact zeros
    }

    // ---- L3: A from st, B streamed from global (L2-resident) ----
    S8 A30, A31;
    A30.u = *(const uint4*)(st + n16 * 72 + quad * 8);
    A31.u = *(const uint4*)(st + n16 * 72 + 32 + quad * 8);
    const uint4* w3g = (const uint4*)(ws + G_W3F);
    unsigned short* x3t = (unsigned short*)(pw + PW_BUF);   // reuse BUF
    const float* b3p = (const float*)(lds + G_B3);
    #pragma unroll
    for (int nt = 0; nt < 8; nt++) {
        float bb = b3p[nt * 16 + n16];
        f32x4 c = {bb, bb, bb, bb};
        S8 bf0, bf1;
        bf0.u = w3g[(nt * 2 + 0) * 64 + lane];
        bf1.u = w3g[(nt * 2 + 1) * 64 + lane];
        c = __builtin_amdgcn_mfma_f32_16x16x32_bf16(A30.v, bf0.v, c, 0, 0, 0);
        c = __builtin_amdgcn_mfma_f32_16x16x32_bf16(A31.v, bf1.v, c, 0, 0, 0);
        #pragma unroll
        for (int r = 0; r < 4; r++)
            x3t[(quad * 4 + r) * 136 + nt * 16 + n16] = bfbits(fmaxf(c[r], 0.f));
    }

    // ---- heads: means|logvar (N=16) ----
    S8 Ah0, Ah1, Ah2, Ah3;
    Ah0.u = *(const uint4*)(x3t + n16 * 136 + 0  + quad * 8);
    Ah1.u = *(const uint4*)(x3t + n16 * 136 + 32 + quad * 8);
    Ah2.u = *(const uint4*)(x3t + n16 * 136 + 64 + quad * 8);
    Ah3.u = *(const uint4*)(x3t + n16 * 136 + 96 + quad * 8);
    float bmvv = *(const float*)(lds + G_BMV + n16 * 4);
    f32x4 cm = {bmvv, bmvv, bmvv, bmvv};
    {
        S8 bm0; bm0.u = *(const uint4*)(lds + G_MVF + (0 * 64 + lane) * 16);
        cm = __builtin_amdgcn_mfma_f32_16x16x32_bf16(Ah0.v, bm0.v, cm, 0, 0, 0);
        S8 bm1; bm1.u = *(const uint4*)(lds + G_MVF + (1 * 64 + lane) * 16);
        cm = __builtin_amdgcn_mfma_f32_16x16x32_bf16(Ah1.v, bm1.v, cm, 0, 0, 0);
        S8 bm2; bm2.u = *(const uint4*)(lds + G_MVF + (2 * 64 + lane) * 16);
        cm = __builtin_amdgcn_mfma_f32_16x16x32_bf16(Ah2.v, bm2.v, cm, 0, 0, 0);
        S8 bm3; bm3.u = *(const uint4*)(lds + G_MVF + (3 * 64 + lane) * 16);
        cm = __builtin_amdgcn_mfma_f32_16x16x32_bf16(Ah3.v, bm3.v, cm, 0, 0, 0);
    }
    float* mlv = (float*)(pw + PW_MH);
    #pragma unroll
    for (int r = 0; r < 4; r++) mlv[(quad * 4 + r) * 18 + n16] = cm[r];

    // ---- reparameterization + means/logvar/z outputs ----
    {
        int r = lane >> 2, g = lane & 3;
        long R = rb + r;
        const float* mrow = mlv + r * 18;
        float2 mn = *(const float2*)(mrow + 2 * g);
        float2 lv = *(const float2*)(mrow + 8 + 2 * g);
        float2 ev = *(const float2*)(eps + R * 8 + 2 * g);
        float z0 = fmaf(ev.x, __expf(0.5f * lv.x), mn.x);
        float z1 = fmaf(ev.y, __expf(0.5f * lv.y), mn.y);
        *(float2*)(out + (long)B * 12 + R * 8 + 2 * g) = mn;
        *(float2*)(out + (long)B * 20 + R * 8 + 2 * g) = lv;
        *(float2*)(out + (long)B * 28 + R * 8 + 2 * g) = make_float2(z0, z1);
        unsigned short* sic = (unsigned short*)(pw + PW_SIC);
        *(unsigned int*)(sic + r * 40 + 12 + 2 * g) = pk(z0, z1);  // k=12..19
    }

    // ---- decoder layer 1 (N=32, K=32) ----
    S8 Ad;
    Ad.u = *(const uint4*)((const unsigned short*)(pw + PW_SIC) + n16 * 40 + quad * 8);
    unsigned short* ht = (unsigned short*)(pw + PW_MH);   // reuse MH (mlv consumed)
    #pragma unroll
    for (int t = 0; t < 2; t++) {
        float dc = *(const float*)(lds + G_D1C + (t * 16 + n16) * 4);
        f32x4 c = {dc, dc, dc, dc};
        S8 bd; bd.u = *(const uint4*)(lds + G_D1F + (t * 64 + lane) * 16);
        c = __builtin_amdgcn_mfma_f32_16x16x32_bf16(Ad.v, bd.v, c, 0, 0, 0);
        #pragma unroll
        for (int r = 0; r < 4; r++)
            ht[(quad * 4 + r) * 40 + t * 16 + n16] = bfbits(fmaxf(c[r], 0.f));
    }

    // ---- decoder layer 2 (N=16, K=32) + sigmoid + recon store ----
    S8 Ah2d; Ah2d.u = *(const uint4*)(ht + n16 * 40 + quad * 8);
    float bd2v = *(const float*)(lds + G_BD2 + n16 * 4);
    f32x4 cr2 = {bd2v, bd2v, bd2v, bd2v};
    S8 b2d; b2d.u = *(const uint4*)(lds + G_D2F + lane * 16);
    cr2 = __builtin_amdgcn_mfma_f32_16x16x32_bf16(Ah2d.v, b2d.v, cr2, 0, 0, 0);
    if (n16 < 12) {
        #pragma unroll
        for (int r = 0; r < 4; r++)
            out[(rb + quad * 4 + r) * 12 + n16] = 1.f / (1.f + __expf(-cr2[r]));
    }
}

extern "C" void kernel_launch(void* const* d_in, const int* in_sizes, int n_in,
                              void* d_out, int out_size, void* d_ws, size_t ws_size,
                              hipStream_t stream) {
    const float* ic  = (const float*)d_in[0];   // initial_c [B,30]
    const float* cc  = (const float*)d_in[2];   // current_c [B,30]
    const float* eps = (const float*)d_in[3];   // eps [B,8]

    const int B = in_sizes[3] / 8;              // 262144
    const int nblocks = B / 64;                 // 4096

    prep_kernel<<<PREP_BLOCKS, TPB, 0, stream>>>(
        (const float*)d_in[4],  (const float*)d_in[5],
        (const float*)d_in[6],  (const float*)d_in[7],
        (const float*)d_in[8],  (const float*)d_in[9],
        (const float*)d_in[10], (const float*)d_in[11],
        (const float*)d_in[12], (const float*)d_in[13],
        (const float*)d_in[14], (const float*)d_in[15],
        (const float*)d_in[16], (const float*)d_in[17],
        (unsigned char*)d_ws);
    vae_mfma<<<nblocks, TPB, 0, stream>>>(
        ic, cc, eps, (const unsigned char*)d_ws, (float*)d_out, B);
}